// Round 1
// baseline (344.364 us; speedup 1.0000x reference)
//
#include <hip/hip_runtime.h>
#include <math.h>

// One wave (64 threads) per batch element; full 300-step time loop in-kernel.
// Phases per step: encoder LIF (regs) -> z to LDS -> conv4x4+maxpool2 (lanes 0..35,
// both channels) -> s_p[72] -> linear 72->10 (lanes 0..39 partials + shfl gather)
// -> decoder LIF + streamed mem/spk stores (lanes 0..9).

__global__ __launch_bounds__(64) void snn_step_kernel(
    const float* __restrict__ x,       // [B,1,15,15]
    const float* __restrict__ conv_w,  // [2,1,4,4]
    const float* __restrict__ conv_b,  // [2]
    const float* __restrict__ lin_w,   // [10,72]
    const float* __restrict__ lin_b,   // [10]
    float* __restrict__ out,           // spk_out[B,10] ++ mem_rec[T,B,10] ++ spk_rec[T,B,10]
    int T, int B)
{
    const int b = blockIdx.x;
    const int l = threadIdx.x;

    __shared__ float s_convw[32];
    __shared__ float s_convb[2];
    __shared__ float s_linw[720];
    __shared__ float s_linb[10];
    __shared__ float s_z[15 * 17];   // stride 17: breaks power-of-2 bank aliasing
    __shared__ float s_p[72];

    // ---- cooperative weight staging ----
    if (l < 32) s_convw[l] = conv_w[l];
    if (l < 2)  s_convb[l] = conv_b[l];
    for (int j = l; j < 720; j += 64) s_linw[j] = lin_w[j];
    if (l < 10) s_linb[l] = lin_b[l];

    // ---- encoder state: pixels l, l+64, l+128, l+192 ----
    float ve[4], cur[4];
    int   zoff[4];
    bool  act[4];
#pragma unroll
    for (int k = 0; k < 4; ++k) {
        int p = l + 64 * k;
        act[k]  = (p < 225);
        ve[k]   = 0.0f;
        cur[k]  = act[k] ? __fmul_rn(x[(size_t)b * 225 + p], 10.0f) : 0.0f;
        zoff[k] = act[k] ? ((p / 15) * 17 + (p % 15)) : 0;
    }

    // ---- decoder state (lanes 0..9 meaningful) ----
    float v = 0.0f, i_syn = 0.0f, sc = 0.0f;

    // ---- conv lane mapping: lane < 36 -> pooled position (py,px) ----
    const bool convlane = (l < 36);
    const int  py = l / 6, px = l - py * 6;
    const int  y0 = 2 * py, x0 = 2 * px;

    // ---- linear lane mapping: lane < 40 -> (output lo, quarter lq) ----
    const bool linlane = (l < 40);
    const int  lo = l >> 2, lq = l & 3;

    const size_t BO = (size_t)B * 10;
    float* mem_rec = out + BO;
    float* spk_rec = out + BO + (size_t)T * BO;

    __syncthreads();

    // conv weights + bias into registers (reused 300x)
    float wreg[2][16];
#pragma unroll
    for (int c = 0; c < 2; ++c)
#pragma unroll
        for (int kk = 0; kk < 16; ++kk) wreg[c][kk] = s_convw[c * 16 + kk];
    const float cb0 = s_convb[0], cb1 = s_convb[1];

    // linear weights slice into registers (18 per lane, reused 300x)
    float lwreg[18];
    if (linlane) {
#pragma unroll
        for (int j = 0; j < 18; ++j) lwreg[j] = s_linw[lo * 72 + lq * 18 + j];
    }
    const float lbias = (l < 10) ? s_linb[l] : 0.0f;

    for (int t = 0; t < T; ++t) {
        // ---------- encoder LIF ----------
#pragma unroll
        for (int k = 0; k < 4; ++k) {
            if (act[k]) {
                // v' = v + 0.1*(cur - v)   (explicit mul/add order, no contraction)
                float vn = __fadd_rn(ve[k], __fmul_rn(0.1f, __fsub_rn(cur[k], ve[k])));
                float z  = (vn > 1.0f) ? 1.0f : 0.0f;
                ve[k]    = (vn > 1.0f) ? 0.0f : vn;   // v - z*v
                s_z[zoff[k]] = z;
            }
        }
        __syncthreads();

        // ---------- conv 4x4 + maxpool 2x2 ----------
        if (convlane) {
            float zr[5][5];
#pragma unroll
            for (int r = 0; r < 5; ++r)
#pragma unroll
                for (int cc = 0; cc < 5; ++cc)
                    zr[r][cc] = s_z[(y0 + r) * 17 + (x0 + cc)];
#pragma unroll
            for (int c = 0; c < 2; ++c) {
                float m = -INFINITY;
#pragma unroll
                for (int dy = 0; dy < 2; ++dy)
#pragma unroll
                    for (int dx = 0; dx < 2; ++dx) {
                        float acc = 0.0f;
#pragma unroll
                        for (int ky = 0; ky < 4; ++ky)
#pragma unroll
                            for (int kx = 0; kx < 4; ++kx)
                                // z in {0,1} => w*z exact => fma == mul+add here
                                acc = fmaf(wreg[c][ky * 4 + kx], zr[dy + ky][dx + kx], acc);
                        float val = __fadd_rn(acc, c ? cb1 : cb0);
                        m = fmaxf(m, val);
                    }
                s_p[c * 36 + l] = m;
            }
        }
        __syncthreads();

        // ---------- linear 72 -> 10 ----------
        float partial = 0.0f;
        if (linlane) {
            const float* pp = &s_p[lq * 18];
#pragma unroll
            for (int j = 0; j < 18; ++j)
                partial = fmaf(lwreg[j], pp[j], partial);
        }
        // gather 4 partials to lanes 0..9 (src lane stays < 64 for all lanes)
        const int base = 4 * (l & 15);
        float p0 = __shfl(partial, base + 0);
        float p1 = __shfl(partial, base + 1);
        float p2 = __shfl(partial, base + 2);
        float p3 = __shfl(partial, base + 3);

        if (l < 10) {
            float lin = __fadd_rn(__fadd_rn(__fadd_rn(__fadd_rn(p0, p1), p2), p3), lbias);

            // ---------- decoder LIF ----------
            float vd  = __fadd_rn(v, __fmul_rn(0.1f, __fsub_rn(i_syn, v)));
            float id  = __fsub_rn(i_syn, __fmul_rn(0.2f, i_syn));
            float spk = (vd > 1.0f) ? 1.0f : 0.0f;
            v     = (vd > 1.0f) ? 0.0f : vd;     // (1-spk)*v_dec
            i_syn = __fadd_rn(id, lin);
            sc += spk;

            size_t off = (size_t)t * BO + (size_t)b * 10 + l;
            mem_rec[off] = v;
            spk_rec[off] = spk;
        }
    }

    if (l < 10) out[(size_t)b * 10 + l] = sc;
}

extern "C" void kernel_launch(void* const* d_in, const int* in_sizes, int n_in,
                              void* d_out, int out_size, void* d_ws, size_t ws_size,
                              hipStream_t stream) {
    const float* x      = (const float*)d_in[0];
    const float* conv_w = (const float*)d_in[1];
    const float* conv_b = (const float*)d_in[2];
    const float* lin_w  = (const float*)d_in[3];
    const float* lin_b  = (const float*)d_in[4];
    // num_steps (d_in[5]) is a device scalar; derive T from host-side out_size instead.
    float* out = (float*)d_out;

    const int B = in_sizes[0] / 225;           // x is [B,1,15,15]
    const int T = (out_size / (B * 10) - 1) / 2; // out = B*10 * (1 + 2T)

    snn_step_kernel<<<B, 64, 0, stream>>>(x, conv_w, conv_b, lin_w, lin_b, out, T, B);
}

// Round 2
// 288.542 us; speedup vs baseline: 1.1935x; 1.1935x over previous
//
#include <hip/hip_runtime.h>
#include <math.h>

// One wave (64 threads) per batch element; full 300-step time loop in-kernel.
// Round 1: (a) swizzled s_z layout addr=row*16+col+3*(row>>1) -> conv-read banks
// (3py+2px) mod 32, max 2-way (free); (b) conv packed across the 2 channels as
// float2 -> v_pk_fma_f32 (per-half numerics identical to scalar fmaf chain);
// (c) branchless encoder writing dead lanes to LDS pad; incremental out pointers.

typedef float v2f __attribute__((ext_vector_type(2)));

__global__ __launch_bounds__(64) void snn_step_kernel(
    const float* __restrict__ x,       // [B,1,15,15]
    const float* __restrict__ conv_w,  // [2,1,4,4]
    const float* __restrict__ conv_b,  // [2]
    const float* __restrict__ lin_w,   // [10,72]
    const float* __restrict__ lin_b,   // [10]
    float* __restrict__ out,           // spk_out[B,10] ++ mem_rec[T,B,10] ++ spk_rec[T,B,10]
    int T, int B)
{
    const int b = blockIdx.x;
    const int l = threadIdx.x;

    __shared__ float s_convw[32];
    __shared__ float s_convb[2];
    __shared__ float s_linw[720];
    __shared__ float s_linb[10];
    __shared__ float s_z[304];   // swizzled 15x15 tile + pad for dead-lane writes
    __shared__ float s_p[72];

    // ---- cooperative weight staging ----
    if (l < 32) s_convw[l] = conv_w[l];
    if (l < 2)  s_convb[l] = conv_b[l];
    for (int j = l; j < 720; j += 64) s_linw[j] = lin_w[j];
    if (l < 10) s_linb[l] = lin_b[l];

    // ---- encoder state: pixels l, l+64, l+128, l+192 (branchless; p>=225 is pad) ----
    float ve[4], cur[4];
    int   zoff[4];
#pragma unroll
    for (int k = 0; k < 4; ++k) {
        int p = l + 64 * k;
        bool act = (p < 225);
        ve[k]  = 0.0f;
        cur[k] = act ? __fmul_rn(x[(size_t)b * 225 + p], 10.0f) : 0.0f;
        int row = p / 15, col = p - row * 15;
        zoff[k] = row * 16 + col + 3 * (row >> 1);   // swizzled; rows>=15 land in pad
    }

    // ---- decoder state (lanes 0..9 meaningful) ----
    float v = 0.0f, i_syn = 0.0f, sc = 0.0f;

    // ---- conv lane mapping: lane < 36 -> pooled position (py,px) ----
    const bool convlane = (l < 36);
    const int  py = l / 6, px = l - py * 6;
    const int  y0 = 2 * py, x0 = 2 * px;

    // ---- linear lane mapping: lane < 40 -> (output lo, quarter lq) ----
    const bool linlane = (l < 40);
    const int  lo = l >> 2, lq = l & 3;

    const size_t BO = (size_t)B * 10;

    __syncthreads();

    // conv weights packed (ch0, ch1) + bias, reused 300x
    v2f wreg2[16];
#pragma unroll
    for (int kk = 0; kk < 16; ++kk) wreg2[kk] = (v2f){s_convw[kk], s_convw[16 + kk]};
    const v2f cb2 = (v2f){s_convb[0], s_convb[1]};

    // linear weights slice into registers (18 per lane, reused 300x)
    float lwreg[18];
    if (linlane) {
#pragma unroll
        for (int j = 0; j < 18; ++j) lwreg[j] = s_linw[lo * 72 + lq * 18 + j];
    }
    const float lbias = (l < 10) ? s_linb[l] : 0.0f;

    // incremental output pointers (uniform advance; only lanes<10 store)
    float* mp  = out + BO + (size_t)b * 10 + l;
    float* spp = out + BO + (size_t)T * BO + (size_t)b * 10 + l;

    for (int t = 0; t < T; ++t) {
        // ---------- encoder LIF (branchless) ----------
#pragma unroll
        for (int k = 0; k < 4; ++k) {
            float vn = __fadd_rn(ve[k], __fmul_rn(0.1f, __fsub_rn(cur[k], ve[k])));
            bool  sp = (vn > 1.0f);
            ve[k] = sp ? 0.0f : vn;
            s_z[zoff[k]] = sp ? 1.0f : 0.0f;
        }
        __syncthreads();

        // ---------- conv 4x4 (both channels packed) + maxpool 2x2 ----------
        if (convlane) {
            float zr[5][5];
#pragma unroll
            for (int r = 0; r < 5; ++r) {
                int row = y0 + r;
                int rb  = row * 16 + 3 * (row >> 1) + x0;
#pragma unroll
                for (int cc = 0; cc < 5; ++cc)
                    zr[r][cc] = s_z[rb + cc];
            }
            v2f m2 = (v2f){-INFINITY, -INFINITY};
#pragma unroll
            for (int dy = 0; dy < 2; ++dy)
#pragma unroll
                for (int dx = 0; dx < 2; ++dx) {
                    v2f acc = (v2f){0.0f, 0.0f};
#pragma unroll
                    for (int ky = 0; ky < 4; ++ky)
#pragma unroll
                        for (int kx = 0; kx < 4; ++kx) {
                            float z = zr[dy + ky][dx + kx];
                            acc = __builtin_elementwise_fma(wreg2[ky * 4 + kx],
                                                            (v2f){z, z}, acc);
                        }
                    v2f val = acc + cb2;                       // v_pk_add
                    m2 = __builtin_elementwise_max(m2, val);   // maxnum per half
                }
            s_p[l]      = m2.x;
            s_p[36 + l] = m2.y;
        }
        __syncthreads();

        // ---------- linear 72 -> 10 (order identical to round 0) ----------
        float partial = 0.0f;
        if (linlane) {
            const float* pp = &s_p[lq * 18];
#pragma unroll
            for (int j = 0; j < 18; ++j)
                partial = fmaf(lwreg[j], pp[j], partial);
        }
        const int base = 4 * (l & 15);
        float p0 = __shfl(partial, base + 0);
        float p1 = __shfl(partial, base + 1);
        float p2 = __shfl(partial, base + 2);
        float p3 = __shfl(partial, base + 3);

        if (l < 10) {
            float lin = __fadd_rn(__fadd_rn(__fadd_rn(__fadd_rn(p0, p1), p2), p3), lbias);

            // ---------- decoder LIF ----------
            float vd  = __fadd_rn(v, __fmul_rn(0.1f, __fsub_rn(i_syn, v)));
            float id  = __fsub_rn(i_syn, __fmul_rn(0.2f, i_syn));
            float spk = (vd > 1.0f) ? 1.0f : 0.0f;
            v     = (vd > 1.0f) ? 0.0f : vd;     // (1-spk)*v_dec
            i_syn = __fadd_rn(id, lin);
            sc += spk;

            *mp  = v;
            *spp = spk;
        }
        mp  += BO;
        spp += BO;
    }

    if (l < 10) out[(size_t)b * 10 + l] = sc;
}

extern "C" void kernel_launch(void* const* d_in, const int* in_sizes, int n_in,
                              void* d_out, int out_size, void* d_ws, size_t ws_size,
                              hipStream_t stream) {
    const float* x      = (const float*)d_in[0];
    const float* conv_w = (const float*)d_in[1];
    const float* conv_b = (const float*)d_in[2];
    const float* lin_w  = (const float*)d_in[3];
    const float* lin_b  = (const float*)d_in[4];
    float* out = (float*)d_out;

    const int B = in_sizes[0] / 225;             // x is [B,1,15,15]
    const int T = (out_size / (B * 10) - 1) / 2; // out = B*10 * (1 + 2T)

    snn_step_kernel<<<B, 64, 0, stream>>>(x, conv_w, conv_b, lin_w, lin_b, out, T, B);
}

// Round 3
// 285.512 us; speedup vs baseline: 1.2061x; 1.0106x over previous
//
#include <hip/hip_runtime.h>
#include <math.h>

// One wave (64 threads) per batch element; 300-step loop in-kernel.
// Round 2: single-wave workgroup -> drop s_barrier entirely (LDS ops of a wave
// complete in order; phase boundaries need only s_waitcnt lgkmcnt(0) + compiler
// fence). Software pipeline: conv window loads issued first, encoder for t+1
// computed into double-buffered s_z during the read shadow. Shuffle gather
// replaced by s_part write + ds_read_b128. Decoder reordered so only the
// i_syn update waits on the linear result.

typedef float v2f __attribute__((ext_vector_type(2)));

#define LDS_FENCE() asm volatile("s_waitcnt lgkmcnt(0)" ::: "memory")

__global__ __launch_bounds__(64) void snn_step_kernel(
    const float* __restrict__ x,       // [B,1,15,15]
    const float* __restrict__ conv_w,  // [2,1,4,4]
    const float* __restrict__ conv_b,  // [2]
    const float* __restrict__ lin_w,   // [10,72]
    const float* __restrict__ lin_b,   // [10]
    float* __restrict__ out,           // spk_out[B,10] ++ mem_rec[T,B,10] ++ spk_rec[T,B,10]
    int T, int B)
{
    const int b = blockIdx.x;
    const int l = threadIdx.x;

    __shared__ float s_convw[32];
    __shared__ float s_convb[2];
    __shared__ float s_linw[720];
    __shared__ float s_linb[10];
    __shared__ float s_z[2][304];   // double-buffered swizzled 15x15 tile (+pad)
    __shared__ float s_p[72];
    __shared__ float s_part[64];

    // ---- cooperative weight staging ----
    if (l < 32) s_convw[l] = conv_w[l];
    if (l < 2)  s_convb[l] = conv_b[l];
    for (int j = l; j < 720; j += 64) s_linw[j] = lin_w[j];
    if (l < 10) s_linb[l] = lin_b[l];

    // ---- encoder state: pixels l, l+64, l+128, l+192 (branchless; p>=225 -> pad) ----
    float ve[4], cur[4];
    int   zoff[4];
#pragma unroll
    for (int k = 0; k < 4; ++k) {
        int p = l + 64 * k;
        bool act = (p < 225);
        ve[k]  = 0.0f;
        cur[k] = act ? __fmul_rn(x[(size_t)b * 225 + p], 10.0f) : 0.0f;
        int row = p / 15, col = p - row * 15;
        zoff[k] = row * 16 + col + 3 * (row >> 1);   // swizzle; rows>=15 land in pad (<304)
    }

    // ---- decoder state (lanes 0..9 meaningful) ----
    float v = 0.0f, i_syn = 0.0f, sc = 0.0f;

    // ---- conv lane mapping: lane < 36 -> pooled position (py,px) ----
    const bool convlane = (l < 36);
    const int  py = l / 6, px = l - py * 6;
    // window base in swizzled layout (row=2py): 35*py + 2*px; clamp so branchless
    // loads on lanes>=36 stay inside the 304-float buffer (max off 74 -> <=303).
    const int  wbase = (35 * py + 2 * px) < 229 ? (35 * py + 2 * px) : 229;

    // ---- linear lane mapping: (output lo, quarter lq); clamp weight idx for l>=40 ----
    const int  lo = l >> 2, lq = l & 3;

    const size_t BO = (size_t)B * 10;

    LDS_FENCE();

    // conv weights packed (ch0, ch1) + bias, reused 300x
    v2f wreg2[16];
#pragma unroll
    for (int kk = 0; kk < 16; ++kk) wreg2[kk] = (v2f){s_convw[kk], s_convw[16 + kk]};
    const v2f cb2 = (v2f){s_convb[0], s_convb[1]};

    // linear weights slice into registers (18 per lane, reused 300x)
    float lwreg[18];
#pragma unroll
    for (int j = 0; j < 18; ++j) {
        int idx = lo * 72 + lq * 18 + j;
        lwreg[j] = s_linw[idx < 720 ? idx : 719];
    }
    const float lbias = (l < 10) ? s_linb[l] : 0.0f;

    // incremental output pointers (uniform advance; only lanes<10 store)
    float* mp  = out + BO + (size_t)b * 10 + l;
    float* spp = out + BO + (size_t)T * BO + (size_t)b * 10 + l;

    // conv read-window offsets: rows r=0..4 at +{0,16,35,51,70}, cols +0..4
    // ---- prologue: encoder step 0 -> buffer 0 ----
#pragma unroll
    for (int k = 0; k < 4; ++k) {
        float vn = __fadd_rn(ve[k], __fmul_rn(0.1f, __fsub_rn(cur[k], ve[k])));
        bool  sp = (vn > 1.0f);
        ve[k] = sp ? 0.0f : vn;
        s_z[0][zoff[k]] = sp ? 1.0f : 0.0f;
    }

    for (int t = 0; t < T; ++t) {
        const float* zcur = &s_z[t & 1][wbase];
        float*       znxt =  s_z[(t + 1) & 1];

        // ---------- A: issue conv window loads (merge to ds_read2_b32) ----------
        float zr[25];
        {
            const int roff[5] = {0, 16, 35, 51, 70};
#pragma unroll
            for (int r = 0; r < 5; ++r)
#pragma unroll
                for (int cc = 0; cc < 5; ++cc)
                    zr[r * 5 + cc] = zcur[roff[r] + cc];
        }

        // ---------- B: encoder for step t+1 into the other buffer ----------
#pragma unroll
        for (int k = 0; k < 4; ++k) {
            float vn = __fadd_rn(ve[k], __fmul_rn(0.1f, __fsub_rn(cur[k], ve[k])));
            bool  sp = (vn > 1.0f);
            ve[k] = sp ? 0.0f : vn;
            znxt[zoff[k]] = sp ? 1.0f : 0.0f;
        }

        LDS_FENCE();   // conv reads + enc writes drained

        // ---------- C: conv 4x4 (channels packed) + maxpool 2x2 ----------
        if (convlane) {
            v2f m2 = (v2f){-INFINITY, -INFINITY};
#pragma unroll
            for (int dy = 0; dy < 2; ++dy)
#pragma unroll
                for (int dx = 0; dx < 2; ++dx) {
                    v2f acc = (v2f){0.0f, 0.0f};
#pragma unroll
                    for (int ky = 0; ky < 4; ++ky)
#pragma unroll
                        for (int kx = 0; kx < 4; ++kx) {
                            float z = zr[(dy + ky) * 5 + (dx + kx)];
                            acc = __builtin_elementwise_fma(wreg2[ky * 4 + kx],
                                                            (v2f){z, z}, acc);
                        }
                    v2f val = acc + cb2;
                    m2 = __builtin_elementwise_max(m2, val);
                }
            s_p[l]      = m2.x;
            s_p[36 + l] = m2.y;
        }

        // ---------- D: linear 72 -> 10 (in-order LDS pipe: reads see s_p writes) ----------
        float pv[18];
        {
            const float* pp = &s_p[lq * 18];
#pragma unroll
            for (int j = 0; j < 18; ++j) pv[j] = pp[j];   // merges to ds_read_b64 x9
        }
        float partial = 0.0f;
#pragma unroll
        for (int j = 0; j < 18; ++j)
            partial = fmaf(lwreg[j], pv[j], partial);
        s_part[l] = partial;

        // issue the 16B gather now (in-order after the s_part writes)
        float4 pr;
        {
            const float4* p4 = (const float4*)&s_part[4 * (l < 10 ? l : 0)];
            pr = *p4;
        }

        // ---------- E: decoder front half (independent of lin) + stores ----------
        float vd  = __fadd_rn(v, __fmul_rn(0.1f, __fsub_rn(i_syn, v)));
        float id  = __fsub_rn(i_syn, __fmul_rn(0.2f, i_syn));
        float spk = (vd > 1.0f) ? 1.0f : 0.0f;
        v = (vd > 1.0f) ? 0.0f : vd;
        sc += spk;
        if (l < 10) {
            *mp  = v;
            *spp = spk;
        }
        mp  += BO;
        spp += BO;

        // ---------- F: finish linear, update i_syn ----------
        float lin = __fadd_rn(__fadd_rn(__fadd_rn(__fadd_rn(pr.x, pr.y), pr.z), pr.w), lbias);
        i_syn = __fadd_rn(id, lin);
    }

    if (l < 10) out[(size_t)b * 10 + l] = sc;
}

extern "C" void kernel_launch(void* const* d_in, const int* in_sizes, int n_in,
                              void* d_out, int out_size, void* d_ws, size_t ws_size,
                              hipStream_t stream) {
    const float* x      = (const float*)d_in[0];
    const float* conv_w = (const float*)d_in[1];
    const float* conv_b = (const float*)d_in[2];
    const float* lin_w  = (const float*)d_in[3];
    const float* lin_b  = (const float*)d_in[4];
    float* out = (float*)d_out;

    const int B = in_sizes[0] / 225;             // x is [B,1,15,15]
    const int T = (out_size / (B * 10) - 1) / 2; // out = B*10 * (1 + 2T)

    snn_step_kernel<<<B, 64, 0, stream>>>(x, conv_w, conv_b, lin_w, lin_b, out, T, B);
}